// Round 18
// baseline (20.487 us; speedup 1.0000x reference)
//
#include <hip/hip_runtime.h>
#include <hip/hip_bf16.h>
#include <math.h>

// Problem constants (from reference)
#define V_SZ 500000
#define E_SZ 128
#define H_SZ 128
#define L_SZ 10
#define P_SZ 10
#define N_SZ 50
#define NSEQ (P_SZ + N_SZ)       // 60 non-phrase sequences
#define NBLK 60                  // block j handles (seq 0, seq j+1)
#define TPB  384                 // 6 waves; wave w owns gate rows [64w, 64w+64)

#define SIG_STRIDE 8             // 64 B between signal words (line separation)
#define FLAG_MAGIC 0x9E370000u

#define GI_STR 388               // gi_all per-col stride (floats): 16B-aligned, ~2-way banks
#define XS_STR 136               // xs_bf16 row stride (bf16): 272B, 16B-aligned

typedef __attribute__((ext_vector_type(8))) short bf16x8;  // 8 bf16 = 4 VGPRs (MFMA A/B frag)
typedef __attribute__((ext_vector_type(4))) float f32x4;   // MFMA C/D frag

#define MFMA(a, b, c) __builtin_amdgcn_mfma_f32_16x16x32_bf16((a), (b), (c), 0, 0, 0)

__device__ __forceinline__ float sigmoidf(float x) {
    return 1.0f / (1.0f + expf(-x));
}

// RNE f32->bf16 via HW converter (v_cvt_pk_bf16_f32) — R16-proven
__device__ __forceinline__ unsigned short f2bf(float f) {
    __hip_bfloat16 h = __float2bfloat16(f);
    unsigned short u;
    __builtin_memcpy(&u, &h, sizeof(u));
    return u;
}

__device__ __forceinline__ unsigned f2bf2(float lo, float hi) {   // packed 2xbf16
    float2 v = make_float2(lo, hi);
    __hip_bfloat162 h2 = __float22bfloat162_rn(v);
    unsigned u;
    __builtin_memcpy(&u, &h2, sizeof(u));
    return u;
}

__device__ __forceinline__ uint2 f2bf4(float4 v) {                // packed 4xbf16
    uint2 r;
    r.x = f2bf2(v.x, v.y);
    r.y = f2bf2(v.z, v.w);
    return r;
}

// R17 structure (proven 20.5 us). R18 change: gi_all de-aliased from the
// weight slab (10 real cols only, 31 KB) so the W_hh staging pass software-
// pipelines (depth-2, 8-load chunks, named buffers) against the gi MFMAs —
// pass-2 load latency hides under compute instead of serializing behind it.
__global__ __launch_bounds__(TPB) void gru_fused(
    const int*   __restrict__ phr_inds,
    const int*   __restrict__ pos_inds,
    const int*   __restrict__ neg_inds,
    const float* __restrict__ u_emb,
    const float* __restrict__ v_emb,
    const float* __restrict__ w_ih,
    const float* __restrict__ w_hh,
    const float* __restrict__ b_ih,
    const float* __restrict__ b_hh,
    const float* __restrict__ h0,
    unsigned long long* __restrict__ sig,   // [NBLK*SIG_STRIDE] workspace
    float*       __restrict__ out)          // f32 scalar
{
    __shared__ __align__(16) unsigned short stage_u[384 * E_SZ];      // 96 KB weight slab
    __shared__ __align__(16) float          gi_all[2 * L_SZ * GI_STR];// 31 KB (10 cols/group)
    __shared__ __align__(16) unsigned short xs_bf16[2][16 * XS_STR];  // x^T per seq-group
    __shared__ __align__(16) float          gh_s[2][3 * H_SZ];        // gh exchange per seq
    __shared__ __align__(16) unsigned short hs_bf16[2][H_SZ];         // h broadcast per seq
    __shared__ __align__(16) float          node[2][H_SZ];            // final h (f32) per seq

    const int bj   = blockIdx.x;             // 0..59
    const int seqB = bj + 1;                 // sequence this block owns (1..60)
    const int t    = threadIdx.x;
    const int lane = t & 63;
    const int wv   = t >> 6;                 // wave 0..5
    const int kg   = lane >> 4;              // k-group 0..3
    const int col  = lane & 15;              // B/D column for this lane
    const int arow = wv * 64 + col;          // A row (lane&15 = row within 16-block)

    // ---- gather x rows for BOTH sequences (deepest-latency loads first) ----
    for (int i = t; i < 2 * L_SZ * 32; i += TPB) {
        const int r  = i >> 5;               // 0..19
        const int e4 = i & 31;
        const int g  = (r < L_SZ) ? 0 : 1;
        const int l  = (r < L_SZ) ? r : r - L_SZ;
        int idx; const float* emb;
        if (g == 0)             { idx = phr_inds[l];                       emb = u_emb; }
        else if (seqB <= P_SZ)  { idx = pos_inds[(seqB - 1) * L_SZ + l];   emb = v_emb; }
        else                    { idx = neg_inds[(seqB - 1 - P_SZ) * L_SZ + l]; emb = v_emb; }
        const float4 v = *reinterpret_cast<const float4*>(emb + (size_t)idx * E_SZ + e4 * 4);
        *reinterpret_cast<uint2*>((char*)&xs_bf16[g][0] + l * (XS_STR * 2) + e4 * 8) = f2bf4(v);
    }

    // ---- biases + h0 early (latency overlap) ----
    const int gseq = t >> 7;                 // 0 or 1 (for t<256)
    const int gu   = t & 127;
    float bih_r = 0.f, bih_z = 0.f, bih_n = 0.f;
    float bhh_r = 0.f, bhh_z = 0.f, bhh_n = 0.f;
    float h_reg = 0.f;
    if (t < 2 * H_SZ) {
        bih_r = b_ih[gu]; bih_z = b_ih[gu + 128]; bih_n = b_ih[gu + 256];
        bhh_r = b_hh[gu]; bhh_z = b_hh[gu + 128]; bhh_n = b_hh[gu + 256];
        h_reg = h0[gu];
        hs_bf16[gseq][gu] = f2bf(h_reg);     // both groups init to h0
    }

    // ---- pass 1: stage w_ih (coalesced -> swizzled slab), read aih frags ----
    bf16x8 aih[4][4], ahh[4][4];
    #pragma unroll 8
    for (int q = 0; q < (384 * E_SZ / 4) / TPB; ++q) {    // 32 iters
        const int fi = q * TPB + t;
        const int lr = fi >> 5;              // row 0..383
        const int e4 = fi & 31;
        const float4 v = *reinterpret_cast<const float4*>(w_ih + (size_t)lr * E_SZ + e4 * 4);
        const int byte = (lr * 256 + e4 * 8) ^ ((lr & 7) << 4);   // G4 XOR-swizzle
        *reinterpret_cast<uint2*>((char*)stage_u + byte) = f2bf4(v);
    }
    __syncthreads();                         // [B1] slab complete (covers xs/hs too)

    #pragma unroll
    for (int mb = 0; mb < 4; ++mb) {
        const int lr = arow + mb * 16;
        #pragma unroll
        for (int kb = 0; kb < 4; ++kb) {
            const int byte = (lr * 256 + kb * 64 + kg * 16) ^ ((lr & 7) << 4);
            aih[mb][kb] = *reinterpret_cast<const bf16x8*>((const char*)stage_u + byte);
        }
    }
    __syncthreads();                         // [B2] aih reads done; slab writable

    // ---- overlap region: pipeline w_hh staging (depth-2 chunks) with gi MFMAs ----
    // chunk c covers q = c*8 .. c*8+7 of the 32-iteration staging loop.
#define LOADW(buf, c)                                                          \
    _Pragma("unroll")                                                          \
    for (int q = 0; q < 8; ++q) {                                              \
        const int fi = ((c) * 8 + q) * TPB + t;                                \
        (buf)[q] = *reinterpret_cast<const float4*>(                           \
            w_hh + (size_t)(fi >> 5) * E_SZ + (fi & 31) * 4);                  \
    }
#define WRITEW(buf, c)                                                         \
    _Pragma("unroll")                                                          \
    for (int q = 0; q < 8; ++q) {                                              \
        const int fi = ((c) * 8 + q) * TPB + t;                                \
        const int lr = fi >> 5;                                                \
        const int byte = (lr * 256 + (fi & 31) * 8) ^ ((lr & 7) << 4);         \
        *reinterpret_cast<uint2*>((char*)stage_u + byte) = f2bf4((buf)[q]);    \
    }
#define GI_HALF(g, h)                                                          \
    _Pragma("unroll")                                                          \
    for (int kbi = 0; kbi < 2; ++kbi) {                                        \
        const int kb = (h) * 2 + kbi;                                          \
        const bf16x8 xb = *reinterpret_cast<const bf16x8*>(                    \
            (const char*)&xs_bf16[(g)][0] + col * (XS_STR * 2) + kb * 64 + kg * 16); \
        ac0 = MFMA(aih[0][kb], xb, ac0);                                       \
        ac1 = MFMA(aih[1][kb], xb, ac1);                                       \
        ac2 = MFMA(aih[2][kb], xb, ac2);                                       \
        ac3 = MFMA(aih[3][kb], xb, ac3);                                       \
    }
#define GI_WRITE(g)                                                            \
    if (col < L_SZ) {                                                          \
        const int rb   = wv * 64 + kg * 4;                                     \
        float* gp = &gi_all[(g) * (L_SZ * GI_STR) + col * GI_STR];             \
        *reinterpret_cast<f32x4*>(gp + rb     ) = ac0;                         \
        *reinterpret_cast<f32x4*>(gp + rb + 16) = ac1;                         \
        *reinterpret_cast<f32x4*>(gp + rb + 32) = ac2;                         \
        *reinterpret_cast<f32x4*>(gp + rb + 48) = ac3;                         \
    }

    {
        float4 va[8], vb[8];
        f32x4 ac0, ac1, ac2, ac3;
        LOADW(va, 0);                        // chunks 0,1 in flight
        LOADW(vb, 1);
        ac0 = ac1 = ac2 = ac3 = (f32x4){0.f, 0.f, 0.f, 0.f};
        GI_HALF(0, 0);                       // gi group 0, kb 0-1 (under load latency)
        WRITEW(va, 0);
        LOADW(va, 2);
        GI_HALF(0, 1);                       // gi group 0, kb 2-3
        GI_WRITE(0);
        WRITEW(vb, 1);
        LOADW(vb, 3);
        ac0 = ac1 = ac2 = ac3 = (f32x4){0.f, 0.f, 0.f, 0.f};
        GI_HALF(1, 0);                       // gi group 1, kb 0-1
        WRITEW(va, 2);
        GI_HALF(1, 1);                       // gi group 1, kb 2-3
        GI_WRITE(1);
        WRITEW(vb, 3);
    }
    __syncthreads();                         // [B3] w_hh slab + gi_all complete

    #pragma unroll
    for (int mb = 0; mb < 4; ++mb) {
        const int lr = arow + mb * 16;
        #pragma unroll
        for (int kb = 0; kb < 4; ++kb) {
            const int byte = (lr * 256 + kb * 64 + kg * 16) ^ ((lr & 7) << 4);
            ahh[mb][kb] = *reinterpret_cast<const bf16x8*>((const char*)stage_u + byte);
        }
    }
    // no barrier needed: slab is never written again; step barriers sync the rest

    // ---- recurrent steps: 16 MFMA/wave/step, cols alternate seq0/seqB ----
    for (int l = 0; l < L_SZ; ++l) {
        f32x4 a0 = {0.f,0.f,0.f,0.f}, a1 = {0.f,0.f,0.f,0.f};
        f32x4 a2 = {0.f,0.f,0.f,0.f}, a3 = {0.f,0.f,0.f,0.f};
        #pragma unroll
        for (int kb = 0; kb < 4; ++kb) {
            // col parity selects which sequence's h this column multiplies
            const bf16x8 bh = *reinterpret_cast<const bf16x8*>(
                (const char*)&hs_bf16[col & 1][0] + kb * 64 + kg * 16);
            a0 = MFMA(ahh[0][kb], bh, a0);
            a1 = MFMA(ahh[1][kb], bh, a1);
            a2 = MFMA(ahh[2][kb], bh, a2);
            a3 = MFMA(ahh[3][kb], bh, a3);
        }
        if (col < 2) {                        // cols 0,1 hold gh for seq0 / seqB
            const int rb = wv * 64 + kg * 4;
            *reinterpret_cast<f32x4*>(&gh_s[col][rb     ]) = a0;
            *reinterpret_cast<f32x4*>(&gh_s[col][rb + 16]) = a1;
            *reinterpret_cast<f32x4*>(&gh_s[col][rb + 32]) = a2;
            *reinterpret_cast<f32x4*>(&gh_s[col][rb + 48]) = a3;
        }
        __syncthreads();                      // [A] gh_s visible

        if (t < 2 * H_SZ) {
            const float* gi = &gi_all[gseq * (L_SZ * GI_STR) + l * GI_STR];
            const float* gh = &gh_s[gseq][0];
            const float r = sigmoidf(gi[gu      ] + bih_r + (gh[gu      ] + bhh_r));
            const float z = sigmoidf(gi[gu + 128] + bih_z + (gh[gu + 128] + bhh_z));
            const float n = tanhf  (gi[gu + 256] + bih_n + r * (gh[gu + 256] + bhh_n));
            h_reg = (1.0f - z) * n + z * h_reg;
            if (l < L_SZ - 1) hs_bf16[gseq][gu] = f2bf(h_reg);  // re-broadcast
            else              node[gseq][gu]   = h_reg;         // final h (f32)
        }
        __syncthreads();                      // [B] hs_bf16 / node visible
    }

    // ---- local dot: s = (node0 . node1) / 128, computed by wave 0 ----
    if (t >= 64) return;                      // no further barriers below

    float d = node[0][t] * node[1][t] + node[0][t + 64] * node[1][t + 64];
    #pragma unroll
    for (int off = 32; off > 0; off >>= 1) d += __shfl_down(d, off);
    const float s_own = d * (1.0f / (float)H_SZ);   // valid in lane 0

    // ---- publish (blocks 1..59) / aggregate (block 0): packed 8-byte signal ----
    if (bj != 0) {
        if (t == 0) {
            const unsigned long long v =
                ((unsigned long long)(FLAG_MAGIC + (unsigned)bj) << 32) |
                (unsigned long long)__float_as_uint(s_own);
            atomicExch(&sig[bj * SIG_STRIDE], v);   // device-scope, idempotent
        }
        return;
    }

    float sv = 0.0f;
    if (t == 0) sv = s_own;
    else if (t < NSEQ) {
        const unsigned want = FLAG_MAGIC + (unsigned)t;
        unsigned long long v;
        do {
            v = atomicAdd(&sig[t * SIG_STRIDE], 0ull);   // coherent 8-byte read
            if ((unsigned)(v >> 32) == want) break;
            __builtin_amdgcn_s_sleep(2);
        } while (true);
        sv = __uint_as_float((unsigned)(v & 0xFFFFFFFFull));
    }

    float vp = 0.0f, vn = 0.0f;
    if (t < P_SZ)      vp = sv;                              // rows 1..10: pos
    else if (t < NSEQ) vn = (sv > 0.0f) ? expf(sv) : 0.0f;   // rows 11..60: neg

    #pragma unroll
    for (int off = 32; off > 0; off >>= 1) {
        vp += __shfl_down(vp, off);
        vn += __shfl_down(vn, off);
    }
    if (t == 0) {
        out[0] = logf(1.0f + vn) - vp;   // -(neg_loss + pos_loss)
    }
}

extern "C" void kernel_launch(void* const* d_in, const int* in_sizes, int n_in,
                              void* d_out, int out_size, void* d_ws, size_t ws_size,
                              hipStream_t stream) {
    const int*   phr_inds = (const int*)  d_in[0];
    const int*   pos_inds = (const int*)  d_in[1];
    const int*   neg_inds = (const int*)  d_in[2];
    const float* u_emb    = (const float*)d_in[3];
    const float* v_emb    = (const float*)d_in[4];
    const float* w_ih     = (const float*)d_in[5];
    const float* w_hh     = (const float*)d_in[6];
    const float* b_ih     = (const float*)d_in[7];
    const float* b_hh     = (const float*)d_in[8];
    const float* h0       = (const float*)d_in[9];

    unsigned long long* sig = (unsigned long long*)d_ws;   // 60 x 64 B signals

    gru_fused<<<NBLK, TPB, 0, stream>>>(phr_inds, pos_inds, neg_inds,
                                        u_emb, v_emb, w_ih, w_hh, b_ih, b_hh, h0,
                                        sig, (float*)d_out);
}